// Round 1
// 498.290 us; speedup vs baseline: 1.2018x; 1.2018x over previous
//
#include <hip/hip_runtime.h>
#include <math.h>

#define BB 64
#define LL 1024
#define DD 1024

typedef __attribute__((ext_vector_type(4))) _Float16 half4;
typedef __attribute__((ext_vector_type(8))) _Float16 half8;
typedef __attribute__((ext_vector_type(4))) float f32x4;

__device__ __forceinline__ float artanh_c(float x){
  x = fminf(fmaxf(x, -1.f + 1e-7f), 1.f - 1e-7f);
  return 0.5f * __logf((1.f + x) / (1.f - x));
}

__device__ __forceinline__ float wave_sum(float v){
  #pragma unroll
  for(int o = 32; o > 0; o >>= 1) v += __shfl_down(v, o, 64);
  return v;
}

// 256-thread (4-wave) block reductions
__device__ __forceinline__ float block_sum4(float v, float* red){
  v = wave_sum(v);
  int wid = threadIdx.x >> 6, lane = threadIdx.x & 63;
  if(lane == 0) red[wid] = v;
  __syncthreads();
  float t = red[0] + red[1] + red[2] + red[3];
  __syncthreads();
  return t;
}

__device__ __forceinline__ float block_max4(float v, float* red){
  #pragma unroll
  for(int o = 32; o > 0; o >>= 1) v = fmaxf(v, __shfl_down(v, o, 64));
  int wid = threadIdx.x >> 6, lane = threadIdx.x & 63;
  if(lane == 0) red[wid] = v;
  __syncthreads();
  float t = fmaxf(fmaxf(red[0], red[1]), fmaxf(red[2], red[3]));
  __syncthreads();
  return t;
}

// K1: q[b,e] = dot(query[b,:], Win[e,:]); wave owns e, loops 16 b; Win row in regs
__global__ void k_qproj(const float* __restrict__ query, const float* __restrict__ Win,
                        float* __restrict__ q){
  int wave = threadIdx.x >> 6, lane = threadIdx.x & 63;
  int e = blockIdx.x * 4 + wave;
  int b0 = blockIdx.y * 16;
  const float4* Wr = (const float4*)(Win + (size_t)e * DD);
  float4 w[4];
  #pragma unroll
  for(int j = 0; j < 4; j++) w[j] = Wr[j * 64 + lane];
  for(int bb = 0; bb < 16; bb++){
    int b = b0 + bb;
    const float4* qr = (const float4*)(query + (size_t)b * DD);
    float acc = 0.f;
    #pragma unroll
    for(int j = 0; j < 4; j++){
      float4 v = qr[j * 64 + lane];
      acc += w[j].x * v.x + w[j].y * v.y + w[j].z * v.z + w[j].w * v.w;
    }
    acc = wave_sum(acc);
    if(lane == 0) q[b * DD + e] = acc;
  }
}

// K2: scores[b,l] = dot(q[b,:], ctx[b,l,:]); wave per (b,l) row; NT loads on fp32 ctx
// (stream, never re-read). Side effect: emit fp16 copy of ctx.
__global__ void k_scores(const float* __restrict__ qv, const float* __restrict__ ctx,
                         float* __restrict__ scores, _Float16* __restrict__ ctx16){
  int b = blockIdx.y;
  int wave = threadIdx.x >> 6, lane = threadIdx.x & 63;
  int l = blockIdx.x * 4 + wave;
  __shared__ float4 qs4[DD / 4];
  qs4[threadIdx.x] = ((const float4*)(qv + (size_t)b * DD))[threadIdx.x];
  __syncthreads();
  const f32x4* cr = (const f32x4*)(ctx + ((size_t)b * LL + l) * DD);
  half4* c16 = (half4*)(ctx16 + ((size_t)b * LL + l) * DD);
  float acc = 0.f;
  #pragma unroll
  for(int it = 0; it < 4; it++){
    int idx = it * 64 + lane;
    f32x4 v = __builtin_nontemporal_load(&cr[idx]);
    float4 qq = qs4[idx];
    acc += qq.x * v.x + qq.y * v.y + qq.z * v.z + qq.w * v.w;
    half4 h;
    h.x = (_Float16)v.x; h.y = (_Float16)v.y; h.z = (_Float16)v.z; h.w = (_Float16)v.w;
    c16[idx] = h;
  }
  acc = wave_sum(acc);
  if(lane == 0) scores[b * LL + l] = acc;
}

// K3: per-b softmax over L, then aw = project(expmap0(aw)); bt = project(expmap0(exp(-ab*dt)))
// 256 threads x 4 elems (float4), 4-wave reductions.
__global__ void k_softmax_tr(const float* __restrict__ scores, const float* __restrict__ dt,
                             const float* __restrict__ ab, const float* __restrict__ cp,
                             float* __restrict__ awt, float* __restrict__ aw_out,
                             float* __restrict__ btt, float* __restrict__ btn){
  __shared__ float red[4];
  int b = blockIdx.x, tid = threadIdx.x;
  float c = cp[0], sc = sqrtf(c), maxn = (1.f - 4e-3f) / sc;
  float4 s = ((const float4*)(scores + (size_t)b * LL))[tid];
  float m = block_max4(fmaxf(fmaxf(s.x, s.y), fmaxf(s.z, s.w)), red);
  float4 e;
  e.x = __expf(s.x - m); e.y = __expf(s.y - m); e.z = __expf(s.z - m); e.w = __expf(s.w - m);
  float Z = block_sum4(e.x + e.y + e.z + e.w, red);
  float inv = 1.f / Z;
  float4 aw;
  aw.x = e.x * inv; aw.y = e.y * inv; aw.z = e.z * inv; aw.w = e.w * inv;
  float S = block_sum4(aw.x * aw.x + aw.y * aw.y + aw.z * aw.z + aw.w * aw.w, red);
  float n = fmaxf(sqrtf(S), 1e-15f);
  float tau = tanhf(sc * n) / (sc * n);
  float n1 = fmaxf(tau * sqrtf(S), 1e-15f);
  float s1 = n1 > maxn ? maxn / n1 : 1.f;
  float f = tau * s1;
  float4 awf;
  awf.x = f * aw.x; awf.y = f * aw.y; awf.z = f * aw.z; awf.w = f * aw.w;
  ((float4*)(awt + (size_t)b * LL))[tid] = awf;
  ((float4*)(aw_out + (size_t)b * LL))[tid] = awf;
  float4 d4 = ((const float4*)(dt + (size_t)b * LL))[tid];
  float abv = ab[b];
  float4 bv;
  bv.x = __expf(-abv * d4.x); bv.y = __expf(-abv * d4.y);
  bv.z = __expf(-abv * d4.z); bv.w = __expf(-abv * d4.w);
  float S2 = block_sum4(bv.x * bv.x + bv.y * bv.y + bv.z * bv.z + bv.w * bv.w, red);
  float n2 = fmaxf(sqrtf(S2), 1e-15f);
  float tau2 = tanhf(sc * n2) / (sc * n2);
  float nb = fmaxf(tau2 * sqrtf(S2), 1e-15f);
  float s2f = nb > maxn ? maxn / nb : 1.f;
  float f2 = tau2 * s2f;
  float4 btf;
  btf.x = f2 * bv.x; btf.y = f2 * bv.y; btf.z = f2 * bv.z; btf.w = f2 * bv.w;
  ((float4*)(btt + (size_t)b * LL))[tid] = btf;
  if(tid == 0) btn[b] = fmaxf(f2 * sqrtf(S2), 1e-15f);
}

// K4: per-(b, l-chunk-128) partial sums; thread owns d-oct (half8 = 16B/lane),
// two 64-row halves per block; NO atomics: each (block,half) writes a private slab
// stats16[b][g][6][D], g = blockIdx.y*2 + h (reduced in k_finish).
// Everything is r^2 times per-row scalars -> hoist w^2, w^2*bt, w^2*bt^2 into LDS.
__global__ __launch_bounds__(256) void k_stats(const _Float16* __restrict__ ctx16,
                        const float* __restrict__ awt,
                        const float* __restrict__ btt, float* __restrict__ stats16){
  int tid = threadIdx.x;
  int b = blockIdx.x;
  int oct = tid & 127, h = tid >> 7;
  int l0 = blockIdx.y * 128;
  __shared__ float w2_[128], w2b_[128], w2b2_[128];
  if(tid < 128){
    float w = awt[b * LL + l0 + tid], bt = btt[b * LL + l0 + tid];
    float w2 = w * w;
    w2_[tid] = w2; w2b_[tid] = w2 * bt; w2b2_[tid] = w2 * bt * bt;
  }
  __syncthreads();
  const half8* cpx = (const half8*)(ctx16 + ((size_t)b * LL + l0 + h * 64) * DD) + oct;
  float r2[8] = {0,0,0,0,0,0,0,0}, p2[8] = {0,0,0,0,0,0,0,0};
  float s3p[8] = {0,0,0,0,0,0,0,0}, s3m[8] = {0,0,0,0,0,0,0,0};
  float s5p[8] = {0,0,0,0,0,0,0,0}, s5m[8] = {0,0,0,0,0,0,0,0};
  #pragma unroll 8
  for(int i = 0; i < 64; i++){
    half8 hv = cpx[(size_t)i * 128];
    int li = h * 64 + i;
    float w2 = w2_[li], w2b = w2b_[li], w2b2 = w2b2_[li];
    #pragma unroll
    for(int j = 0; j < 8; j++){
      float r = (float)hv[j];
      float rsq = r * r;
      float rp2 = r > 0.f ? rsq : 0.f;
      float rn2 = rsq - rp2;
      r2[j] += rsq;
      p2[j] = fmaf(w2, rsq, p2[j]);
      s3p[j] = fmaf(w2b2, rp2, s3p[j]);
      s3m[j] = fmaf(w2b2, rn2, s3m[j]);
      s5p[j] = fmaf(w2b, rp2, s5p[j]);
      s5m[j] = fmaf(w2b, rn2, s5m[j]);
    }
  }
  float* sl = stats16 + (((size_t)b * 16 + (size_t)blockIdx.y * 2 + h) * 6) * DD + oct * 8;
  #define ST_(sidx, arr) { float4* o = (float4*)(sl + (sidx) * DD); \
    o[0] = make_float4(arr[0], arr[1], arr[2], arr[3]); \
    o[1] = make_float4(arr[4], arr[5], arr[6], arr[7]); }
  ST_(0, r2) ST_(1, p2) ST_(2, s3p) ST_(3, s3m) ST_(4, s5p) ST_(5, s5m)
  #undef ST_
}

// K5: reduce 16 stat slabs, then per-row scalar chain -> U, Vp, Vm
__global__ void k_finish(const float* __restrict__ stats16, const float* __restrict__ ae,
                         const float* __restrict__ btn, const float* __restrict__ cp,
                         float* __restrict__ rowsc){
  int row = blockIdx.x * 256 + threadIdx.x;     // row = b*DD + d
  int b = row >> 10;
  int d = row & (DD - 1);
  float c = cp[0], sc = sqrtf(c), maxn = (1.f - 4e-3f) / sc;
  const float* st = stats16 + (size_t)b * 16 * 6 * DD + d;
  float r2 = 0.f, p2 = 0.f, s3p = 0.f, s3m = 0.f, s5p = 0.f, s5m = 0.f;
  #pragma unroll
  for(int g = 0; g < 16; g++){
    const float* sg = st + (size_t)g * 6 * DD;
    r2 += sg[0]; p2 += sg[DD]; s3p += sg[2 * DD];
    s3m += sg[3 * DD]; s5p += sg[4 * DD]; s5m += sg[5 * DD];
  }
  float sp2 = sqrtf(p2);
  // mobius_pointwise_mul(aw, ctx_col) + project  -> mix = beta * p
  float xn  = fmaxf(sqrtf(r2), 1e-15f);
  float wxn = fmaxf(sp2, 1e-15f);
  float at1 = artanh_c(sc * xn);
  float alpha = tanhf(wxn / xn * at1) / (wxn * sc);
  float n1 = fmaxf(alpha * sp2, 1e-15f);
  float beta = alpha * (n1 > maxn ? maxn / n1 : 1.f);
  // mobius_pointwise_mul(ae, mix) + project  -> tmp = g * p
  float aeb = ae[b];
  float mixn_raw = beta * sp2;
  float xn2  = fmaxf(mixn_raw, 1e-15f);
  float wxn2 = fmaxf(fabsf(aeb) * mixn_raw, 1e-15f);
  float at2 = artanh_c(sc * xn2);
  float coef_t = tanhf(wxn2 / xn2 * at2) * aeb * beta / (wxn2 * sc);
  float n2 = fmaxf(fabsf(coef_t) * sp2, 1e-15f);
  float g = coef_t * (n2 > maxn ? maxn / n2 : 1.f);
  // mobius_pointwise_mul(tmp, bt) + project  -> tmp2 = k * (p .* bt)
  float s3 = s3p + s3m;
  float sq3 = sqrtf(s3);
  float xn3 = btn[b];
  float wxn3 = fmaxf(fabsf(g) * sq3, 1e-15f);
  float at3 = artanh_c(sc * xn3);
  float coef2 = tanhf(wxn3 / xn3 * at3) * g / (wxn3 * sc);
  float n3 = fmaxf(fabsf(coef2) * sq3, 1e-15f);
  float k = coef2 * (n3 > maxn ? maxn / n3 : 1.f);
  // term2 = relu(k * p .* bt): nonzero where sign(r) == sign(k)
  bool kp = k > 0.f;
  float ssel  = kp ? s3p : s3m;
  float s5sel = kp ? s5p : s5m;
  float y2 = k * k * ssel;
  float xy = beta * k * s5sel;
  float x2 = beta * beta * p2;
  float A  = 1.f + 2.f * c * xy + c * y2;
  float Bc = 1.f - c * x2;
  float den = 1.f + 2.f * c * xy + c * c * x2 * y2;
  den = fmaxf(den, 1e-15f);
  float U0 = A * beta / den;
  float V0 = Bc * k / den;
  float nf2 = U0 * U0 * p2 + 2.f * U0 * V0 * s5sel + V0 * V0 * ssel;
  float nf = fmaxf(sqrtf(nf2), 1e-15f);
  float s4 = nf > maxn ? maxn / nf : 1.f;
  float U = U0 * s4, V = V0 * s4;
  float4* out4 = (float4*)(rowsc + (size_t)row * 4);
  *out4 = make_float4(U, kp ? V : 0.f, kp ? 0.f : V, 0.f);
}

// K6 (fused, fp16 ctx): 32 rows per block.
//   phase 1: colsum per row (wave-per-row, half8 16B/lane) -> lam
//   phase 2: nom partial per d-quad (re-read, L2-hot) -> private slab nom32[b][chunk][D]
__global__ __launch_bounds__(256) void k_mixagg(const _Float16* __restrict__ ctx16,
                         const float* __restrict__ awt, const float* __restrict__ btt,
                         const float* __restrict__ rowsc, const float* __restrict__ cp,
                         float* __restrict__ lam_out, float* __restrict__ nom32){
  __shared__ float aw_s[32], bt_s[32], lam_s[32];
  int b = blockIdx.y;
  int l0 = blockIdx.x * 32;
  int tid = threadIdx.x, wave = tid >> 6, lane = tid & 63;
  float c = cp[0];
  if(tid < 32){ aw_s[tid] = awt[b * LL + l0 + tid]; bt_s[tid] = btt[b * LL + l0 + tid]; }
  // preload rowsc: wave-layout (phase 1) d=(it*64+lane)*8+j
  float U1[2][8], Vp1[2][8], Vm1[2][8];
  const float4* rp = (const float4*)rowsc + (size_t)b * DD;
  #pragma unroll
  for(int it = 0; it < 2; it++){
    int o = it * 64 + lane;
    #pragma unroll
    for(int j = 0; j < 8; j++){
      float4 t = rp[o * 8 + j];
      U1[it][j] = t.x; Vp1[it][j] = t.y; Vm1[it][j] = t.z;
    }
  }
  // preload rowsc: quad-layout (phase 2) d=tid*4+j
  float U2[4], Vp2[4], Vm2[4];
  #pragma unroll
  for(int j = 0; j < 4; j++){
    float4 t = rp[tid * 4 + j];
    U2[j] = t.x; Vp2[j] = t.y; Vm2[j] = t.z;
  }
  __syncthreads();
  const half8* cb8 = (const half8*)(ctx16 + (size_t)b * LL * DD);
  // phase 1: wave w handles rows w, w+4, ..., w+28; acc = sum (rc*uv)^2, scale by w^2 once
  #pragma unroll
  for(int rr = 0; rr < 8; rr++){
    int r = wave + rr * 4;
    int l = l0 + r;
    float w = aw_s[r], bt = bt_s[r];
    float acc = 0.f;
    #pragma unroll
    for(int it = 0; it < 2; it++){
      half8 hv = cb8[(size_t)l * 128 + it * 64 + lane];
      #pragma unroll
      for(int j = 0; j < 8; j++){
        float rc = (float)hv[j];
        float t = rc > 0.f ? Vp1[it][j] : Vm1[it][j];
        float uv = fmaf(bt, t, U1[it][j]);
        float mvs = rc * uv;
        acc = fmaf(mvs, mvs, acc);
      }
    }
    acc = wave_sum(acc);
    if(lane == 0){
      float lv = 2.f / fmaxf(1.f - c * (w * w) * acc, 1e-15f);
      lam_s[r] = lv;
      lam_out[b * LL + l] = lv;
    }
  }
  __syncthreads();
  // phase 2: thread owns d-quad, accumulate nom over 32 rows (reads are L2-hot)
  float acc2[4] = {0, 0, 0, 0};
  const half4* cb4 = (const half4*)(ctx16 + (size_t)b * LL * DD);
  #pragma unroll 4
  for(int r = 0; r < 32; r++){
    float bt = bt_s[r];
    float lw = lam_s[r] * aw_s[r];
    half4 hv = cb4[(size_t)(l0 + r) * 256 + tid];
    float rx[4] = {(float)hv.x, (float)hv.y, (float)hv.z, (float)hv.w};
    #pragma unroll
    for(int j = 0; j < 4; j++){
      float rc = rx[j];
      float t = rc > 0.f ? Vp2[j] : Vm2[j];
      float mv = rc * fmaf(bt, t, U2[j]);
      acc2[j] = fmaf(lw, mv, acc2[j]);
    }
  }
  ((float4*)(nom32 + ((size_t)b * 32 + blockIdx.x) * DD))[tid] =
      make_float4(acc2[0], acc2[1], acc2[2], acc2[3]);
}

// K7a: reduce nom slabs; den from lam; tm = nom/den; midpoint half-scalar-mul; logmap0;
// combined = [mixl, q]. 256 threads x float4.
__global__ void k_mid(const float* __restrict__ nom32, const float* __restrict__ lam,
                      const float* __restrict__ qv, const float* __restrict__ cp,
                      float* __restrict__ comb){
  __shared__ float red[4];
  int b = blockIdx.x, tid = threadIdx.x;
  float c = cp[0], sc = sqrtf(c);
  float4 lv = ((const float4*)(lam + (size_t)b * LL))[tid];
  float dsum = block_sum4(lv.x + lv.y + lv.z + lv.w - 4.f, red);
  float den = dsum >= 0.f ? fmaxf(dsum, 1e-10f) : fminf(dsum, -1e-10f);
  float nx = 0.f, ny = 0.f, nz = 0.f, nw = 0.f;
  #pragma unroll
  for(int k = 0; k < 32; k++){
    float4 t = ((const float4*)(nom32 + ((size_t)b * 32 + k) * DD))[tid];
    nx += t.x; ny += t.y; nz += t.z; nw += t.w;
  }
  float tx = nx / den, ty = ny / den, tz = nz / den, tw = nw / den;
  float S = block_sum4(tx * tx + ty * ty + tz * tz + tw * tw, red);
  float n = fmaxf(sqrtf(S), 1e-15f);
  float at = artanh_c(sc * n);
  float mu = tanhf(0.5f * at) / (sc * n);
  float n2 = fmaxf(mu * sqrtf(S), 1e-15f);
  float nu = artanh_c(sc * n2) / (sc * n2);
  float f = nu * mu;
  float4 q4 = ((const float4*)(qv + (size_t)b * DD))[tid];
  ((float4*)(comb + (size_t)b * 2 * DD))[tid] = make_float4(f * tx, f * ty, f * tz, f * tw);
  ((float4*)(comb + (size_t)b * 2 * DD + DD))[tid] = q4;
}

// K7b: out[b,d] = tanh(dot(comb[b,:], Wout[d,:])); wave owns d, loops 16 b; Wout row in regs
__global__ void k_out(const float* __restrict__ comb, const float* __restrict__ Wout,
                      float* __restrict__ outp){
  int wave = threadIdx.x >> 6, lane = threadIdx.x & 63;
  int d = blockIdx.x * 4 + wave;
  int b0 = blockIdx.y * 16;
  const float4* Wr = (const float4*)(Wout + (size_t)d * 2 * DD);
  float4 w[8];
  #pragma unroll
  for(int j = 0; j < 8; j++) w[j] = Wr[j * 64 + lane];
  for(int bb = 0; bb < 16; bb++){
    int b = b0 + bb;
    const float4* cb = (const float4*)(comb + (size_t)b * 2 * DD);
    float acc = 0.f;
    #pragma unroll
    for(int j = 0; j < 8; j++){
      float4 v = cb[j * 64 + lane];
      acc += w[j].x * v.x + w[j].y * v.y + w[j].z * v.z + w[j].w * v.w;
    }
    acc = wave_sum(acc);
    if(lane == 0) outp[b * DD + d] = tanhf(acc);
  }
}

extern "C" void kernel_launch(void* const* d_in, const int* in_sizes, int n_in,
                              void* d_out, int out_size, void* d_ws, size_t ws_size,
                              hipStream_t stream) {
  const float* query = (const float*)d_in[0];
  const float* ctx   = (const float*)d_in[1];
  const float* dt    = (const float*)d_in[2];
  const float* cp    = (const float*)d_in[3];
  const float* Win   = (const float*)d_in[4];
  const float* Wout  = (const float*)d_in[5];
  const float* ae    = (const float*)d_in[6];
  const float* ab    = (const float*)d_in[7];
  float* out = (float*)d_out;
  float* ws  = (float*)d_ws;

  // ws layout (floats) — every buffer fully rewritten each run (poison-safe, no memset)
  float* q_       = ws;                  // 65536
  float* awt_     = ws + 65536;          // 65536
  float* btt_     = ws + 131072;         // 65536
  float* btn_     = ws + 196608;         // 64 (+pad)
  float* scores_  = ws + 196736;         // 65536 (reused as lam)
  float* rowsc_   = ws + 262272;         // 262144 [row][4] = (U,Vp,Vm,0)
  float* comb_    = ws + 524416;         // 131072
  float* stats16_ = ws + 655488;         // 64*16*6*1024 = 6291456
  float* nom32_   = ws + 6946944;        // 64*32*1024 = 2097152
  _Float16* ctx16_ = (_Float16*)(ws + 9044096); // 64M halves = 128 MB
  float* lam_ = scores_;

  k_qproj     <<<dim3(256, 4),  256, 0, stream>>>(query, Win, q_);
  k_scores    <<<dim3(256, BB), 256, 0, stream>>>(q_, ctx, scores_, ctx16_);
  k_softmax_tr<<<BB,            256, 0, stream>>>(scores_, dt, ab, cp, awt_, out + BB * DD, btt_, btn_);
  k_stats     <<<dim3(BB, 8),   256, 0, stream>>>(ctx16_, awt_, btt_, stats16_);
  k_finish    <<<256,           256, 0, stream>>>(stats16_, ae, btn_, cp, rowsc_);
  k_mixagg    <<<dim3(32, BB),  256, 0, stream>>>(ctx16_, awt_, btt_, rowsc_, cp, lam_, nom32_);
  k_mid       <<<BB,            256, 0, stream>>>(nom32_, lam_, q_, cp, comb_);
  k_out       <<<dim3(256, 4),  256, 0, stream>>>(comb_, Wout, out);
}